// Round 4
// baseline (155.163 us; speedup 1.0000x reference)
//
#include <hip/hip_runtime.h>
#include <hip/hip_bf16.h>

// DeepQNetwork MoE as a sorted grouped GEMM with split-bf16 MFMA.
// 3 launches: prep_histo (vectorized weight frags + expert histogram)
//          -> scan_scatter (per-block shfl scan + ballot-rank scatter)
//          -> mlp_mfma (32 rows/WAVE = 2 m-tiles in flight, 1 expert/block)

#define NE   8
#define DIM  256
#define HID  64
#define NA   18

typedef __attribute__((ext_vector_type(8))) short short8;
typedef __attribute__((ext_vector_type(4))) float f32x4;
#define MFMA __builtin_amdgcn_mfma_f32_16x16x32_bf16

// ---------- bf16 split helpers ----------
__device__ __forceinline__ unsigned short f2bf(float f) {     // RNE scalar
    unsigned u = __builtin_bit_cast(unsigned, f);
    u += 0x7fff + ((u >> 16) & 1);
    return (unsigned short)(u >> 16);
}
__device__ __forceinline__ float bf2f(unsigned short h) {
    unsigned u = ((unsigned)h) << 16;
    return __builtin_bit_cast(float, u);
}
__device__ __forceinline__ void split8v(const float* xs, short8& hi, short8& lo) {
    float back[8];
    #pragma unroll
    for (int p = 0; p < 4; ++p) {
        __hip_bfloat162 h2 = __float22bfloat162_rn(make_float2(xs[2*p], xs[2*p+1]));
        hi[2*p]   = (short)__builtin_bit_cast(unsigned short, h2.x);
        hi[2*p+1] = (short)__builtin_bit_cast(unsigned short, h2.y);
        float2 b2 = __bfloat1622float2(h2);
        back[2*p] = b2.x; back[2*p+1] = b2.y;
    }
    #pragma unroll
    for (int p = 0; p < 4; ++p) {
        __hip_bfloat162 l2 = __float22bfloat162_rn(
            make_float2(xs[2*p] - back[2*p], xs[2*p+1] - back[2*p+1]));
        lo[2*p]   = (short)__builtin_bit_cast(unsigned short, l2.x);
        lo[2*p+1] = (short)__builtin_bit_cast(unsigned short, l2.y);
    }
}

// ---------- kernel 1: weight frag (8 elems/thread) + histogram ----------
// prep units: (e,ks,nt,l) -> j=0..7.  W1: 16384 units, W2..5: 16384, W6: 2048.
// 34816 units = 136 blocks; histo blocks [136, 136+256).
__global__ __launch_bounds__(256) void prep_histo(
    const float* __restrict__ W1, const float* __restrict__ W2,
    const float* __restrict__ W3, const float* __restrict__ W4,
    const float* __restrict__ W5, const float* __restrict__ W6,
    short* __restrict__ W1H, short* __restrict__ W1L,
    short* __restrict__ W2H, short* __restrict__ W2L,
    short* __restrict__ W3H, short* __restrict__ W3L,
    short* __restrict__ W4H, short* __restrict__ W4L,
    short* __restrict__ W5H, short* __restrict__ W5L,
    short* __restrict__ W6H, short* __restrict__ W6L,
    const int* __restrict__ rm, int* __restrict__ hist) {
    const int bid = blockIdx.x;
    if (bid >= 136) {                         // ---- histogram ----
        __shared__ int wch[4][NE];
        const int blk = bid - 136;
        const int t = threadIdx.x, w = t >> 6, l = t & 63;
        const int e = rm[blk * 256 + t];
        #pragma unroll
        for (int q = 0; q < NE; ++q) {
            unsigned long long m = __ballot(e == q);
            if (l == 0) wch[w][q] = __popcll(m);
        }
        __syncthreads();
        if (t < NE) hist[blk * NE + t] = wch[0][t] + wch[1][t] + wch[2][t] + wch[3][t];
        return;
    }
    const int u = bid * 256 + threadIdx.x;    // ---- prep ----
    const float* src; int sstride, dbase, n, npad;
    short *H, *L;
    if (u < 16384) {                          // W1: e(3) ks(3) nt(2) l(6)
        int e = u >> 11, r = u & 2047;
        int ks = r >> 8, nt = (r >> 6) & 3, l = r & 63;
        int k0 = ks * 32 + ((l >> 4) << 3); n = (nt << 4) + (l & 15);
        src = W1 + ((size_t)(e * DIM + k0)) * HID + n;
        sstride = HID; npad = HID;
        H = W1H; L = W1L; dbase = e * 16384 + ((ks * 4 + nt) * 64 + l) * 8;
    } else if (u < 32768) {                   // W2..5: layer(2) e(3) ks(1) nt(2) l(6)
        int u2 = u - 16384;
        int layer = u2 >> 12, local = u2 & 4095;
        int e = local >> 9, r = local & 511;
        int ks = r >> 8, nt = (r >> 6) & 3, l = r & 63;
        int k0 = ks * 32 + ((l >> 4) << 3); n = (nt << 4) + (l & 15);
        const float* W = (layer == 0) ? W2 : (layer == 1) ? W3 : (layer == 2) ? W4 : W5;
        src = W + ((size_t)(e * HID + k0)) * HID + n;
        sstride = HID; npad = HID;
        H = (layer == 0) ? W2H : (layer == 1) ? W3H : (layer == 2) ? W4H : W5H;
        L = (layer == 0) ? W2L : (layer == 1) ? W3L : (layer == 2) ? W4L : W5L;
        dbase = e * 4096 + ((ks * 4 + nt) * 64 + l) * 8;
    } else {                                  // W6: e(3) ks(1) nt(1) l(6), N pad->32
        int u3 = u - 32768;
        int e = u3 >> 8, r = u3 & 255;
        int ks = r >> 7, nt = (r >> 6) & 1, l = r & 63;
        int k0 = ks * 32 + ((l >> 4) << 3); n = (nt << 4) + (l & 15);
        src = W6 + ((size_t)(e * HID + k0)) * NA + n;
        sstride = NA; npad = NA;
        H = W6H; L = W6L; dbase = e * 2048 + ((ks * 2 + nt) * 64 + l) * 8;
    }
    short8 hs, ls;
    #pragma unroll
    for (int j = 0; j < 8; ++j) {
        float v = (n < npad) ? src[j * sstride] : 0.0f;
        unsigned short h = f2bf(v);
        hs[j] = (short)h;
        ls[j] = (short)f2bf(v - bf2f(h));
    }
    *(short8*)(H + dbase) = hs;
    *(short8*)(L + dbase) = ls;
}

// ---------- kernel 2: fused scan + scatter ----------
// meta[0..7]=counts  meta[8..16]=expertStart  meta[17..25]=tile128Start
__global__ __launch_bounds__(512) void scan_scatter(const int* __restrict__ rm,
                                                    const int* __restrict__ hist,
                                                    int* __restrict__ perm,
                                                    int* __restrict__ meta) {
    __shared__ int sbuf[NE][256];
    __shared__ int wc[8][NE];
    __shared__ int wb2[4][NE];
    __shared__ int baseE[NE];
    const int t = threadIdx.x, w = t >> 6, l = t & 63;
    const int myblk = blockIdx.x;

    {   // scan: wave w handles expert w
        int v0 = hist[(l * 4 + 0) * NE + w];
        int v1 = hist[(l * 4 + 1) * NE + w];
        int v2 = hist[(l * 4 + 2) * NE + w];
        int v3 = hist[(l * 4 + 3) * NE + w];
        v1 += v0; v2 += v1; v3 += v2;
        int s = v3;
        #pragma unroll
        for (int off = 1; off < 64; off <<= 1) {
            int u = __shfl_up(s, off);
            if (l >= off) s += u;
        }
        const int ex = s - v3;
        sbuf[w][l * 4 + 0] = ex + v0;
        sbuf[w][l * 4 + 1] = ex + v1;
        sbuf[w][l * 4 + 2] = ex + v2;
        sbuf[w][l * 4 + 3] = ex + v3;
    }
    __syncthreads();
    if (t < NE) {
        int es = 0;
        for (int q = 0; q < t; ++q) es += sbuf[q][255];
        baseE[t] = es + (myblk ? sbuf[t][myblk - 1] : 0);
    }
    if (myblk == 0 && t == 0) {
        int es = 0, ts = 0;
        meta[8] = 0; meta[17] = 0;
        for (int e = 0; e < NE; ++e) {
            int c = sbuf[e][255];
            meta[e] = c;
            es += c; meta[8 + e + 1] = es;
            ts += (c + 127) >> 7; meta[17 + e + 1] = ts;   // 128-row blocks
        }
    }
    const int i = myblk * 256 + t;
    const int e_row = (t < 256) ? rm[i] : -1;
    const unsigned long long ltm = (1ull << l) - 1ull;
    int rank = 0;
    #pragma unroll
    for (int q = 0; q < NE; ++q) {
        unsigned long long m = __ballot(e_row == q);
        if (e_row == q) rank = __popcll(m & ltm);
        if (l == 0) wc[w][q] = __popcll(m);
    }
    __syncthreads();
    if (t < 32) {
        int ww = t >> 3, q = t & 7;
        int b = baseE[q];
        for (int p = 0; p < ww; ++p) b += wc[p][q];
        wb2[ww][q] = b;
    }
    __syncthreads();
    if (t < 256) perm[wb2[w][e_row] + rank] = i;
}

// ---------- kernel 3: MFMA MLP, 32 rows per wave (2 m-tiles in flight) ----------
template <int NT>
__device__ __forceinline__ void gemm2_k64(const float* h0, const float* h1, int l,
                                          const short* __restrict__ WH,
                                          const short* __restrict__ WL,
                                          f32x4 (*a0)[NT], f32x4 (*a1)[NT],
                                          f32x4 (*a2)[NT]) {
    const int lg = l >> 4, lr = l & 15;
    #pragma unroll
    for (int ks = 0; ks < 2; ++ks) {
        const float* ap0 = h0 + lr * 68 + ks * 32 + lg * 8;
        const float* ap1 = h1 + lr * 68 + ks * 32 + lg * 8;
        float4 u0 = *(const float4*)(ap0);
        float4 u1 = *(const float4*)(ap0 + 4);
        float4 v0 = *(const float4*)(ap1);
        float4 v1 = *(const float4*)(ap1 + 4);
        float xs0[8] = {u0.x, u0.y, u0.z, u0.w, u1.x, u1.y, u1.z, u1.w};
        float xs1[8] = {v0.x, v0.y, v0.z, v0.w, v1.x, v1.y, v1.z, v1.w};
        short8 ahi0, alo0, ahi1, alo1;
        split8v(xs0, ahi0, alo0);
        split8v(xs1, ahi1, alo1);
        short8 bh[NT], bl[NT];
        #pragma unroll
        for (int nt = 0; nt < NT; ++nt) {
            bh[nt] = *(const short8*)(WH + ((ks * NT + nt) * 64 + l) * 8);
            bl[nt] = *(const short8*)(WL + ((ks * NT + nt) * 64 + l) * 8);
        }
        #pragma unroll
        for (int nt = 0; nt < NT; ++nt) {
            a0[0][nt] = MFMA(ahi0, bh[nt], a0[0][nt], 0, 0, 0);
            a0[1][nt] = MFMA(ahi1, bh[nt], a0[1][nt], 0, 0, 0);
            a1[0][nt] = MFMA(alo0, bh[nt], a1[0][nt], 0, 0, 0);
            a1[1][nt] = MFMA(alo1, bh[nt], a1[1][nt], 0, 0, 0);
            a2[0][nt] = MFMA(ahi0, bl[nt], a2[0][nt], 0, 0, 0);
            a2[1][nt] = MFMA(ahi1, bl[nt], a2[1][nt], 0, 0, 0);
        }
    }
}

template <int NT, bool RELU>
__device__ __forceinline__ void finish2(float* h0, float* h1, int l,
                                        const float* __restrict__ bias,
                                        f32x4 (*a0)[NT], f32x4 (*a1)[NT],
                                        f32x4 (*a2)[NT]) {
    const int lg = l >> 4, lr = l & 15;
    #pragma unroll
    for (int nt = 0; nt < NT; ++nt) {
        float bv = bias[nt * 16 + lr];
        #pragma unroll
        for (int r = 0; r < 4; ++r) {
            float v0 = (a0[0][nt][r] + a1[0][nt][r]) + (a2[0][nt][r] + bv);
            float v1 = (a0[1][nt][r] + a1[1][nt][r]) + (a2[1][nt][r] + bv);
            if (RELU) { v0 = fmaxf(v0, 0.0f); v1 = fmaxf(v1, 0.0f); }
            h0[(lg * 4 + r) * 68 + nt * 16 + lr] = v0;  // D: row=(l>>4)*4+r, col=l&15
            h1[(lg * 4 + r) * 68 + nt * 16 + lr] = v1;
        }
    }
}

__global__ __launch_bounds__(256, 2) void mlp_mfma(
    const float* __restrict__ x, const int* __restrict__ perm,
    const int* __restrict__ meta,
    const short* __restrict__ W1H, const short* __restrict__ W1L,
    const short* __restrict__ W2H, const short* __restrict__ W2L,
    const short* __restrict__ W3H, const short* __restrict__ W3L,
    const short* __restrict__ W4H, const short* __restrict__ W4L,
    const short* __restrict__ W5H, const short* __restrict__ W5L,
    const short* __restrict__ W6H, const short* __restrict__ W6L,
    const float* __restrict__ b1, const float* __restrict__ b2,
    const float* __restrict__ b3, const float* __restrict__ b4,
    const float* __restrict__ b5, const float* __restrict__ b6,
    float* __restrict__ out) {
    __shared__ __align__(16) float hbuf[4][2][16][68];   // 34816 B
    const int blk = blockIdx.x;
    if (blk >= meta[17 + NE]) return;
    int e = 0;
    #pragma unroll 1
    while (blk >= meta[17 + e + 1]) ++e;
    const int lt = blk - meta[17 + e];
    const int cnt = meta[e];
    const int pbase = meta[8 + e];
    const int t = threadIdx.x, w = t >> 6, l = t & 63;
    const int lg = l >> 4, lr = l & 15;
    const int li0 = lt * 128 + w * 32 + lr;        // m-tile 0 row
    const int li1 = li0 + 16;                      // m-tile 1 row
    const int row0 = perm[pbase + min(li0, cnt - 1)];
    const int row1 = perm[pbase + min(li1, cnt - 1)];
    float* h0 = &hbuf[w][0][0][0];
    float* h1 = &hbuf[w][1][0][0];
    const f32x4 zero = {0.0f, 0.0f, 0.0f, 0.0f};

    // ---- layer 1: x[row][256] @ W1 -> h[2][16][64] ----
    {
        f32x4 a0[2][4], a1[2][4], a2[2][4];
        #pragma unroll
        for (int m = 0; m < 2; ++m)
            #pragma unroll
            for (int nt = 0; nt < 4; ++nt) { a0[m][nt] = zero; a1[m][nt] = zero; a2[m][nt] = zero; }
        const float* xr0 = x + (size_t)row0 * DIM + lg * 8;
        const float* xr1 = x + (size_t)row1 * DIM + lg * 8;
        const short* WHp = W1H + (size_t)e * 16384 + l * 8;
        const short* WLp = W1L + (size_t)e * 16384 + l * 8;
        #pragma unroll
        for (int ks = 0; ks < 8; ++ks) {
            float4 u0 = *(const float4*)(xr0 + ks * 32);
            float4 u1 = *(const float4*)(xr0 + ks * 32 + 4);
            float4 v0 = *(const float4*)(xr1 + ks * 32);
            float4 v1 = *(const float4*)(xr1 + ks * 32 + 4);
            float xs0[8] = {u0.x, u0.y, u0.z, u0.w, u1.x, u1.y, u1.z, u1.w};
            float xs1[8] = {v0.x, v0.y, v0.z, v0.w, v1.x, v1.y, v1.z, v1.w};
            short8 ahi0, alo0, ahi1, alo1;
            split8v(xs0, ahi0, alo0);
            split8v(xs1, ahi1, alo1);
            short8 bh[4], bl[4];
            #pragma unroll
            for (int nt = 0; nt < 4; ++nt) {
                bh[nt] = *(const short8*)(WHp + (ks * 4 + nt) * 512);
                bl[nt] = *(const short8*)(WLp + (ks * 4 + nt) * 512);
            }
            #pragma unroll
            for (int nt = 0; nt < 4; ++nt) {
                a0[0][nt] = MFMA(ahi0, bh[nt], a0[0][nt], 0, 0, 0);
                a0[1][nt] = MFMA(ahi1, bh[nt], a0[1][nt], 0, 0, 0);
                a1[0][nt] = MFMA(alo0, bh[nt], a1[0][nt], 0, 0, 0);
                a1[1][nt] = MFMA(alo1, bh[nt], a1[1][nt], 0, 0, 0);
                a2[0][nt] = MFMA(ahi0, bl[nt], a2[0][nt], 0, 0, 0);
                a2[1][nt] = MFMA(ahi1, bl[nt], a2[1][nt], 0, 0, 0);
            }
        }
        finish2<4, true>(h0, h1, l, b1 + e * HID, a0, a1, a2);
    }
    // ---- layers 2..5 ----
    #define HIDDEN(WH_, WL_, bias_)                                         \
    {                                                                       \
        f32x4 a0[2][4], a1[2][4], a2[2][4];                                 \
        _Pragma("unroll")                                                   \
        for (int m = 0; m < 2; ++m)                                         \
            _Pragma("unroll")                                               \
            for (int nt = 0; nt < 4; ++nt) { a0[m][nt] = zero; a1[m][nt] = zero; a2[m][nt] = zero; } \
        gemm2_k64<4>(h0, h1, l, WH_ + e * 4096, WL_ + e * 4096, a0, a1, a2);\
        finish2<4, true>(h0, h1, l, bias_ + e * HID, a0, a1, a2);           \
    }
    HIDDEN(W2H, W2L, b2)
    HIDDEN(W3H, W3L, b3)
    HIDDEN(W4H, W4L, b4)
    HIDDEN(W5H, W5L, b5)
    #undef HIDDEN
    // ---- layer 6 + scatter store ----
    {
        f32x4 a0[2][2], a1[2][2], a2[2][2];
        #pragma unroll
        for (int m = 0; m < 2; ++m)
            #pragma unroll
            for (int nt = 0; nt < 2; ++nt) { a0[m][nt] = zero; a1[m][nt] = zero; a2[m][nt] = zero; }
        gemm2_k64<2>(h0, h1, l, W6H + e * 2048, W6L + e * 2048, a0, a1, a2);
        const float* b6p = b6 + e * NA;
        #pragma unroll
        for (int m = 0; m < 2; ++m) {
            const int rowm = m ? row1 : row0;
            #pragma unroll
            for (int r = 0; r < 4; ++r) {
                const int drow = lg * 4 + r;
                const int rs = __shfl(rowm, drow, 64);
                const bool valid = (lt * 128 + w * 32 + m * 16 + drow) < cnt;
                #pragma unroll
                for (int nt = 0; nt < 2; ++nt) {
                    const int col = nt * 16 + lr;
                    if (valid && col < NA)
                        out[(size_t)rs * NA + col] =
                            (a0[m][nt][r] + a1[m][nt][r]) + (a2[m][nt][r] + b6p[col]);
                }
            }
        }
    }
}

extern "C" void kernel_launch(void* const* d_in, const int* in_sizes, int n_in,
                              void* d_out, int out_size, void* d_ws, size_t ws_size,
                              hipStream_t stream) {
    const float* x  = (const float*)d_in[0];
    const int*   rm = (const int*)d_in[1];
    const float* W1 = (const float*)d_in[2];   const float* b1 = (const float*)d_in[3];
    const float* W2 = (const float*)d_in[4];   const float* b2 = (const float*)d_in[5];
    const float* W3 = (const float*)d_in[6];   const float* b3 = (const float*)d_in[7];
    const float* W4 = (const float*)d_in[8];   const float* b4 = (const float*)d_in[9];
    const float* W5 = (const float*)d_in[10];  const float* b5 = (const float*)d_in[11];
    const float* W6 = (const float*)d_in[12];  const float* b6 = (const float*)d_in[13];
    float* out = (float*)d_out;

    const int B = in_sizes[1];                 // 65536
    const int nblk = B / 256;                  // 256

    // ws layout:
    int* hist = (int*)d_ws;                    // nblk*8
    int* meta = hist + nblk * NE;              // 32
    int* perm = meta + 32;                     // B
    short* W1H = (short*)(perm + B);           // frag buffers
    short* W1L = W1H + 131072;
    short* W2H = W1L + 131072;  short* W2L = W2H + 32768;
    short* W3H = W2L + 32768;   short* W3L = W3H + 32768;
    short* W4H = W3L + 32768;   short* W4L = W4H + 32768;
    short* W5H = W4L + 32768;   short* W5L = W5H + 32768;
    short* W6H = W5L + 32768;   short* W6L = W6H + 16384;

    prep_histo<<<136 + nblk, 256, 0, stream>>>(W1, W2, W3, W4, W5, W6,
                                               W1H, W1L, W2H, W2L, W3H, W3L,
                                               W4H, W4L, W5H, W5L, W6H, W6L,
                                               rm, hist);
    scan_scatter<<<nblk, 512, 0, stream>>>(rm, hist, perm, meta);
    mlp_mfma<<<B / 128 + NE, 256, 0, stream>>>(x, perm, meta,
                                               W1H, W1L, W2H, W2L, W3H, W3L,
                                               W4H, W4L, W5H, W5L, W6H, W6L,
                                               b1, b2, b3, b4, b5, b6, out);
}

// Round 5
// 153.106 us; speedup vs baseline: 1.0134x; 1.0134x over previous
//
#include <hip/hip_runtime.h>
#include <hip/hip_bf16.h>

// DeepQNetwork MoE as a sorted grouped GEMM with split-bf16 MFMA.
// R5: K-split waves. Block = 4 waves = 32 rows; wave (m,kh) owns a 16-row
// m-tile and HALF of K. Partial sums exchanged via LDS each layer.
// 8192 waves -> 8 waves/SIMD (VGPR<=64 via launch_bounds(256,8)).

#define NE   8
#define DIM  256
#define HID  64
#define NA   18

typedef __attribute__((ext_vector_type(8))) short short8;
typedef __attribute__((ext_vector_type(4))) float f32x4;
#define MFMA __builtin_amdgcn_mfma_f32_16x16x32_bf16

// ---------- bf16 split helpers ----------
__device__ __forceinline__ unsigned short f2bf(float f) {     // RNE scalar
    unsigned u = __builtin_bit_cast(unsigned, f);
    u += 0x7fff + ((u >> 16) & 1);
    return (unsigned short)(u >> 16);
}
__device__ __forceinline__ float bf2f(unsigned short h) {
    unsigned u = ((unsigned)h) << 16;
    return __builtin_bit_cast(float, u);
}
__device__ __forceinline__ void split8v(const float* xs, short8& hi, short8& lo) {
    float back[8];
    #pragma unroll
    for (int p = 0; p < 4; ++p) {
        __hip_bfloat162 h2 = __float22bfloat162_rn(make_float2(xs[2*p], xs[2*p+1]));
        hi[2*p]   = (short)__builtin_bit_cast(unsigned short, h2.x);
        hi[2*p+1] = (short)__builtin_bit_cast(unsigned short, h2.y);
        float2 b2 = __bfloat1622float2(h2);
        back[2*p] = b2.x; back[2*p+1] = b2.y;
    }
    #pragma unroll
    for (int p = 0; p < 4; ++p) {
        __hip_bfloat162 l2 = __float22bfloat162_rn(
            make_float2(xs[2*p] - back[2*p], xs[2*p+1] - back[2*p+1]));
        lo[2*p]   = (short)__builtin_bit_cast(unsigned short, l2.x);
        lo[2*p+1] = (short)__builtin_bit_cast(unsigned short, l2.y);
    }
}

// ---------- kernel 1: weight frag (8 elems/thread) + histogram ----------
__global__ __launch_bounds__(256) void prep_histo(
    const float* __restrict__ W1, const float* __restrict__ W2,
    const float* __restrict__ W3, const float* __restrict__ W4,
    const float* __restrict__ W5, const float* __restrict__ W6,
    short* __restrict__ W1H, short* __restrict__ W1L,
    short* __restrict__ W2H, short* __restrict__ W2L,
    short* __restrict__ W3H, short* __restrict__ W3L,
    short* __restrict__ W4H, short* __restrict__ W4L,
    short* __restrict__ W5H, short* __restrict__ W5L,
    short* __restrict__ W6H, short* __restrict__ W6L,
    const int* __restrict__ rm, int* __restrict__ hist) {
    const int bid = blockIdx.x;
    if (bid >= 136) {                         // ---- histogram ----
        __shared__ int wch[4][NE];
        const int blk = bid - 136;
        const int t = threadIdx.x, w = t >> 6, l = t & 63;
        const int e = rm[blk * 256 + t];
        #pragma unroll
        for (int q = 0; q < NE; ++q) {
            unsigned long long m = __ballot(e == q);
            if (l == 0) wch[w][q] = __popcll(m);
        }
        __syncthreads();
        if (t < NE) hist[blk * NE + t] = wch[0][t] + wch[1][t] + wch[2][t] + wch[3][t];
        return;
    }
    const int u = bid * 256 + threadIdx.x;    // ---- prep ----
    const float* src; int sstride, dbase, n, npad;
    short *H, *L;
    if (u < 16384) {                          // W1
        int e = u >> 11, r = u & 2047;
        int ks = r >> 8, nt = (r >> 6) & 3, l = r & 63;
        int k0 = ks * 32 + ((l >> 4) << 3); n = (nt << 4) + (l & 15);
        src = W1 + ((size_t)(e * DIM + k0)) * HID + n;
        sstride = HID; npad = HID;
        H = W1H; L = W1L; dbase = e * 16384 + ((ks * 4 + nt) * 64 + l) * 8;
    } else if (u < 32768) {                   // W2..5
        int u2 = u - 16384;
        int layer = u2 >> 12, local = u2 & 4095;
        int e = local >> 9, r = local & 511;
        int ks = r >> 8, nt = (r >> 6) & 3, l = r & 63;
        int k0 = ks * 32 + ((l >> 4) << 3); n = (nt << 4) + (l & 15);
        const float* W = (layer == 0) ? W2 : (layer == 1) ? W3 : (layer == 2) ? W4 : W5;
        src = W + ((size_t)(e * HID + k0)) * HID + n;
        sstride = HID; npad = HID;
        H = (layer == 0) ? W2H : (layer == 1) ? W3H : (layer == 2) ? W4H : W5H;
        L = (layer == 0) ? W2L : (layer == 1) ? W3L : (layer == 2) ? W4L : W5L;
        dbase = e * 4096 + ((ks * 4 + nt) * 64 + l) * 8;
    } else {                                  // W6 (N pad->32)
        int u3 = u - 32768;
        int e = u3 >> 8, r = u3 & 255;
        int ks = r >> 7, nt = (r >> 6) & 1, l = r & 63;
        int k0 = ks * 32 + ((l >> 4) << 3); n = (nt << 4) + (l & 15);
        src = W6 + ((size_t)(e * HID + k0)) * NA + n;
        sstride = NA; npad = NA;
        H = W6H; L = W6L; dbase = e * 2048 + ((ks * 2 + nt) * 64 + l) * 8;
    }
    short8 hs, ls;
    #pragma unroll
    for (int j = 0; j < 8; ++j) {
        float v = (n < npad) ? src[j * sstride] : 0.0f;
        unsigned short h = f2bf(v);
        hs[j] = (short)h;
        ls[j] = (short)f2bf(v - bf2f(h));
    }
    *(short8*)(H + dbase) = hs;
    *(short8*)(L + dbase) = ls;
}

// ---------- kernel 2: fused scan + scatter ----------
// meta[0..7]=counts  meta[8..16]=expertStart  meta[17..25]=tile32Start
__global__ __launch_bounds__(512) void scan_scatter(const int* __restrict__ rm,
                                                    const int* __restrict__ hist,
                                                    int* __restrict__ perm,
                                                    int* __restrict__ meta) {
    __shared__ int sbuf[NE][256];
    __shared__ int wc[8][NE];
    __shared__ int wb2[4][NE];
    __shared__ int baseE[NE];
    const int t = threadIdx.x, w = t >> 6, l = t & 63;
    const int myblk = blockIdx.x;

    {   // scan: wave w handles expert w
        int v0 = hist[(l * 4 + 0) * NE + w];
        int v1 = hist[(l * 4 + 1) * NE + w];
        int v2 = hist[(l * 4 + 2) * NE + w];
        int v3 = hist[(l * 4 + 3) * NE + w];
        v1 += v0; v2 += v1; v3 += v2;
        int s = v3;
        #pragma unroll
        for (int off = 1; off < 64; off <<= 1) {
            int u = __shfl_up(s, off);
            if (l >= off) s += u;
        }
        const int ex = s - v3;
        sbuf[w][l * 4 + 0] = ex + v0;
        sbuf[w][l * 4 + 1] = ex + v1;
        sbuf[w][l * 4 + 2] = ex + v2;
        sbuf[w][l * 4 + 3] = ex + v3;
    }
    __syncthreads();
    if (t < NE) {
        int es = 0;
        for (int q = 0; q < t; ++q) es += sbuf[q][255];
        baseE[t] = es + (myblk ? sbuf[t][myblk - 1] : 0);
    }
    if (myblk == 0 && t == 0) {
        int es = 0, ts = 0;
        meta[8] = 0; meta[17] = 0;
        for (int e = 0; e < NE; ++e) {
            int c = sbuf[e][255];
            meta[e] = c;
            es += c; meta[8 + e + 1] = es;
            ts += (c + 31) >> 5; meta[17 + e + 1] = ts;    // 32-row tiles
        }
    }
    const int i = myblk * 256 + t;
    const int e_row = (t < 256) ? rm[i] : -1;
    const unsigned long long ltm = (1ull << l) - 1ull;
    int rank = 0;
    #pragma unroll
    for (int q = 0; q < NE; ++q) {
        unsigned long long m = __ballot(e_row == q);
        if (e_row == q) rank = __popcll(m & ltm);
        if (l == 0) wc[w][q] = __popcll(m);
    }
    __syncthreads();
    if (t < 32) {
        int ww = t >> 3, q = t & 7;
        int b = baseE[q];
        for (int p = 0; p < ww; ++p) b += wc[p][q];
        wb2[ww][q] = b;
    }
    __syncthreads();
    if (t < 256) perm[wb2[w][e_row] + rank] = i;
}

// ---------- kernel 3: K-split MFMA MLP ----------
// read partials pA+pB at this wave's k-slice, relu, split to bf16 hi/lo
__device__ __forceinline__ void read_split(const float* pa, const float* pb, int off,
                                           short8& hi, short8& lo) {
    float4 a0 = *(const float4*)(pa + off);
    float4 a1 = *(const float4*)(pa + off + 4);
    float4 b0 = *(const float4*)(pb + off);
    float4 b1 = *(const float4*)(pb + off + 4);
    float xs[8] = {fmaxf(a0.x + b0.x, 0.0f), fmaxf(a0.y + b0.y, 0.0f),
                   fmaxf(a0.z + b0.z, 0.0f), fmaxf(a0.w + b0.w, 0.0f),
                   fmaxf(a1.x + b1.x, 0.0f), fmaxf(a1.y + b1.y, 0.0f),
                   fmaxf(a1.z + b1.z, 0.0f), fmaxf(a1.w + b1.w, 0.0f)};
    split8v(xs, hi, lo);
}

template <int NT>
__device__ __forceinline__ void mfma_slice(const short* __restrict__ WH,
                                           const short* __restrict__ WL,
                                           int l, int kh,
                                           const short8& ahi, const short8& alo,
                                           f32x4* acc) {
    #pragma unroll
    for (int nt = 0; nt < NT; ++nt) {
        short8 bh = *(const short8*)(WH + (kh * NT + nt) * 512 + l * 8);
        short8 bl = *(const short8*)(WL + (kh * NT + nt) * 512 + l * 8);
        acc[nt] = MFMA(ahi, bh, acc[nt], 0, 0, 0);
        acc[nt] = MFMA(alo, bh, acc[nt], 0, 0, 0);
        acc[nt] = MFMA(ahi, bl, acc[nt], 0, 0, 0);
    }
}

template <int NT>
__device__ __forceinline__ void write_partial(float* pw, int l,
                                              const float* __restrict__ bias,  // null for kh=1
                                              const f32x4* acc) {
    const int lg = l >> 4, lr = l & 15;
    #pragma unroll
    for (int nt = 0; nt < NT; ++nt) {
        float bv = bias ? bias[nt * 16 + lr] : 0.0f;
        #pragma unroll
        for (int r = 0; r < 4; ++r)
            pw[(lg * 4 + r) * 68 + nt * 16 + lr] = acc[nt][r] + bv;  // D: row=(l>>4)*4+r, col=l&15
    }
}

__global__ __launch_bounds__(256, 8) void mlp_mfma(
    const float* __restrict__ x, const int* __restrict__ perm,
    const int* __restrict__ meta,
    const short* __restrict__ W1H, const short* __restrict__ W1L,
    const short* __restrict__ W2H, const short* __restrict__ W2L,
    const short* __restrict__ W3H, const short* __restrict__ W3L,
    const short* __restrict__ W4H, const short* __restrict__ W4L,
    const short* __restrict__ W5H, const short* __restrict__ W5L,
    const short* __restrict__ W6H, const short* __restrict__ W6L,
    const float* __restrict__ b1, const float* __restrict__ b2,
    const float* __restrict__ b3, const float* __restrict__ b4,
    const float* __restrict__ b5, const float* __restrict__ b6,
    float* __restrict__ out) {
    __shared__ __align__(16) float hbuf[2][2][16][68];   // [kh partial][m][row][col], 17408 B
    const int blk = blockIdx.x;
    if (blk >= meta[17 + NE]) return;
    int e = 0;
    #pragma unroll 1
    while (blk >= meta[17 + e + 1]) ++e;
    const int lt = blk - meta[17 + e];
    const int cnt = meta[e];
    const int pbase = meta[8 + e];
    const int t = threadIdx.x, w = t >> 6, l = t & 63;
    const int m = w >> 1, kh = w & 1;
    const int lg = l >> 4, lr = l & 15;
    const int li = lt * 32 + m * 16 + lr;
    const int row = perm[pbase + min(li, cnt - 1)];

    float* pw = &hbuf[kh][m][0][0];
    const float* pa = &hbuf[0][m][0][0];
    const float* pb = &hbuf[1][m][0][0];
    const int roff = lr * 68 + kh * 32 + lg * 8;          // read offset for K=64 layers
    const f32x4 zero = {0.0f, 0.0f, 0.0f, 0.0f};

    // ---- layer 1: K=256, this wave covers k in [kh*128, kh*128+128) ----
    {
        f32x4 a0[4] = {zero, zero, zero, zero};
        f32x4 a1[4] = {zero, zero, zero, zero};
        const float* xr = x + (size_t)row * DIM + kh * 128 + lg * 8;
        const short* WHp = W1H + (size_t)e * 16384;
        const short* WLp = W1L + (size_t)e * 16384;
        #pragma unroll
        for (int ks = 0; ks < 4; ++ks) {
            float4 u0 = *(const float4*)(xr + ks * 32);
            float4 u1 = *(const float4*)(xr + ks * 32 + 4);
            float xs[8] = {u0.x, u0.y, u0.z, u0.w, u1.x, u1.y, u1.z, u1.w};
            short8 ahi, alo; split8v(xs, ahi, alo);
            const int ksg = kh * 4 + ks;
            #pragma unroll
            for (int nt = 0; nt < 4; ++nt) {
                short8 bh = *(const short8*)(WHp + (ksg * 4 + nt) * 512 + l * 8);
                short8 bl = *(const short8*)(WLp + (ksg * 4 + nt) * 512 + l * 8);
                a0[nt] = MFMA(ahi, bh, a0[nt], 0, 0, 0);
                a1[nt] = MFMA(alo, bh, a1[nt], 0, 0, 0);
                a1[nt] = MFMA(ahi, bl, a1[nt], 0, 0, 0);
            }
        }
        f32x4 acc[4];
        #pragma unroll
        for (int nt = 0; nt < 4; ++nt) acc[nt] = a0[nt] + a1[nt];
        write_partial<4>(pw, l, (kh == 0) ? b1 + e * HID : nullptr, acc);
    }
    __syncthreads();

    // ---- layers 2..5: K=64, wave covers k in [kh*32, kh*32+32) ----
    #define HIDDEN(WH_, WL_, bias_)                                          \
    {                                                                        \
        short8 ahi, alo;                                                     \
        read_split(pa, pb, roff, ahi, alo);                                  \
        __syncthreads();  /* reads done before overwrite */                  \
        f32x4 acc[4] = {zero, zero, zero, zero};                             \
        mfma_slice<4>(WH_ + e * 4096, WL_ + e * 4096, l, kh, ahi, alo, acc); \
        write_partial<4>(pw, l, (kh == 0) ? bias_ + e * HID : nullptr, acc); \
        __syncthreads();  /* writes visible for next read */                 \
    }
    HIDDEN(W2H, W2L, b2)
    HIDDEN(W3H, W3L, b3)
    HIDDEN(W4H, W4L, b4)
    HIDDEN(W5H, W5L, b5)
    #undef HIDDEN

    // ---- layer 6: K=64 -> 32 cols (18 used), partials summed at store ----
    {
        short8 ahi, alo;
        read_split(pa, pb, roff, ahi, alo);
        __syncthreads();
        f32x4 acc[2] = {zero, zero};
        mfma_slice<2>(W6H + e * 2048, W6L + e * 2048, l, kh, ahi, alo, acc);
        write_partial<2>(pw, l, nullptr, acc);
        __syncthreads();
    }
    // store: 2 m-tiles x 16 rows x 18 cols = 576 elems over 256 threads
    const float* b6p = b6 + e * NA;
    #pragma unroll
    for (int idx = t; idx < 2 * 16 * NA; idx += 256) {
        const int m2 = idx / (16 * NA);
        const int rr = (idx % (16 * NA)) / NA;
        const int c  = idx % NA;
        const int gr = lt * 32 + m2 * 16 + rr;
        if (gr < cnt) {
            const int rowid = perm[pbase + gr];
            out[(size_t)rowid * NA + c] =
                hbuf[0][m2][rr][c] + hbuf[1][m2][rr][c] + b6p[c];
        }
    }
}

extern "C" void kernel_launch(void* const* d_in, const int* in_sizes, int n_in,
                              void* d_out, int out_size, void* d_ws, size_t ws_size,
                              hipStream_t stream) {
    const float* x  = (const float*)d_in[0];
    const int*   rm = (const int*)d_in[1];
    const float* W1 = (const float*)d_in[2];   const float* b1 = (const float*)d_in[3];
    const float* W2 = (const float*)d_in[4];   const float* b2 = (const float*)d_in[5];
    const float* W3 = (const float*)d_in[6];   const float* b3 = (const float*)d_in[7];
    const float* W4 = (const float*)d_in[8];   const float* b4 = (const float*)d_in[9];
    const float* W5 = (const float*)d_in[10];  const float* b5 = (const float*)d_in[11];
    const float* W6 = (const float*)d_in[12];  const float* b6 = (const float*)d_in[13];
    float* out = (float*)d_out;

    const int B = in_sizes[1];                 // 65536
    const int nblk = B / 256;                  // 256

    // ws layout:
    int* hist = (int*)d_ws;                    // nblk*8
    int* meta = hist + nblk * NE;              // 32
    int* perm = meta + 32;                     // B
    short* W1H = (short*)(perm + B);           // frag buffers
    short* W1L = W1H + 131072;
    short* W2H = W1L + 131072;  short* W2L = W2H + 32768;
    short* W3H = W2L + 32768;   short* W3L = W3H + 32768;
    short* W4H = W3L + 32768;   short* W4L = W4H + 32768;
    short* W5H = W4L + 32768;   short* W5L = W5H + 32768;
    short* W6H = W5L + 32768;   short* W6L = W6H + 16384;

    prep_histo<<<136 + nblk, 256, 0, stream>>>(W1, W2, W3, W4, W5, W6,
                                               W1H, W1L, W2H, W2L, W3H, W3L,
                                               W4H, W4L, W5H, W5L, W6H, W6L,
                                               rm, hist);
    scan_scatter<<<nblk, 512, 0, stream>>>(rm, hist, perm, meta);
    mlp_mfma<<<B / 32 + NE, 256, 0, stream>>>(x, perm, meta,
                                              W1H, W1L, W2H, W2L, W3H, W3L,
                                              W4H, W4L, W5H, W5L, W6H, W6L,
                                              b1, b2, b3, b4, b5, b6, out);
}